// Round 1
// baseline (3714.609 us; speedup 1.0000x reference)
//
#include <hip/hip_runtime.h>
#include <hip/hip_fp16.h>

#define EPS 1e-5f
#define P_TOT 1152
#define SLOT 61952          // halfs per per-patch ws slot (= 128*22*22); h2 uses first 36864

// d_ws requirement: 1152 * 61952 * 2 = 142,737,408 bytes.

__device__ __forceinline__ float2 h2f2(uint32_t u) {
    union { uint32_t u; __half2 h; } cv; cv.u = u;
    return __half22float2(cv.h);
}

// Swizzled LDS byte address for [pix][ci64] half tiles (128B rows).
// 8B-granule 4-bit XOR: spreads the row-stride-128B window reads over 16
// bank-pairs (~4-way residual conflict instead of 64-way).
__device__ __forceinline__ int lds_addr(int pix, int ciByte) {
    return pix * 128 + (ciByte ^ ((pix & 15) << 3));
}

// ---------------- K1: patchify + conv1 + conv2 (fused per patch) ----------------
__global__ __launch_bounds__(512, 2)
void k_conv12(const float* __restrict__ x,
              const float* __restrict__ w1, const float* __restrict__ b1,
              const float* __restrict__ g1, const float* __restrict__ be1,
              const float* __restrict__ m1, const float* __restrict__ v1,
              const float* __restrict__ w2, const float* __restrict__ b2,
              const float* __restrict__ g2, const float* __restrict__ be2,
              const float* __restrict__ m2, const float* __restrict__ v2,
              __half* __restrict__ hws)
{
    extern __shared__ char smem[];
    float* patch = reinterpret_cast<float*>(smem);   // 28*28 fp32 = 3136 B
    char* s1 = smem + 3136;                          // 676 rows * 128 B (swizzled fp16) = 86528 B

    const int p = blockIdx.x;
    const int tid = threadIdx.x;
    const int lane = tid & 63;
    const int wave = tid >> 6;

    // ---- patchify: p = b*9 + hb*3 + wb ; pixel (y,x) -> x[b,0,hb*28+y,wb*28+x]
    {
        const int b = p / 9, r9 = p - b * 9, hb = r9 / 3, wb = r9 - hb * 3;
        const float* xb = x + (size_t)b * 7056 + hb * 28 * 84 + wb * 28;
        for (int i = tid; i < 784; i += 512) {
            const int yy = i / 28, xx = i - yy * 28;
            patch[i] = xb[yy * 84 + xx];
        }
    }
    __syncthreads();

    // ---- conv1 (cin=1): co = lane (so s1 writes are contiguous per wave), pix = wave + 8k
    {
        const int co = lane;
        float wr[9];
        #pragma unroll
        for (int t = 0; t < 9; ++t) wr[t] = w1[co * 9 + t];
        const float sc = g1[co] * rsqrtf(v1[co] + EPS);
        const float sh = be1[co] - (m1[co] - b1[co]) * sc;
        for (int pix = wave; pix < 676; pix += 8) {
            const int yy = pix / 26, xx = pix - yy * 26;
            const float* pp = patch + yy * 28 + xx;
            float acc = 0.f;
            #pragma unroll
            for (int ky = 0; ky < 3; ++ky)
                #pragma unroll
                for (int kx = 0; kx < 3; ++kx)
                    acc = fmaf(pp[ky * 28 + kx], wr[ky * 3 + kx], acc);
            const float v = fmaxf(fmaf(acc, sc, sh), 0.f);
            *reinterpret_cast<__half*>(s1 + lds_addr(pix, co * 2)) = __float2half(v);
        }
    }
    __syncthreads();

    // ---- conv2: lane owns a 3x3 output tile of 24x24; wave processes 4-co blocks
    const int ly = lane >> 3, lx = lane & 7;
    const int y0 = ly * 3, x0 = lx * 3;
    __half* h2p = hws + (size_t)p * SLOT;  // h2 layout [pix24x24][ci64] fp16, linear

    for (int kco = 0; kco < 2; ++kco) {
        const int co0 = (wave + 8 * kco) * 4;
        float acc[3][3][4];
        #pragma unroll
        for (int r = 0; r < 3; ++r)
            #pragma unroll
            for (int c = 0; c < 3; ++c)
                #pragma unroll
                for (int j = 0; j < 4; ++j) acc[r][c][j] = 0.f;

        for (int cib = 0; cib < 16; ++cib) {   // 4 ci per step
            const int ci8 = cib * 8;           // byte offset within row
            float win[5][5][4];                // 5x5 input window, 4 ci (fully static idx)
            #pragma unroll
            for (int r = 0; r < 5; ++r)
                #pragma unroll
                for (int c = 0; c < 5; ++c) {
                    const int pix = (y0 + r) * 26 + (x0 + c);
                    const uint2 raw = *reinterpret_cast<const uint2*>(s1 + lds_addr(pix, ci8));
                    const float2 f01 = h2f2(raw.x), f23 = h2f2(raw.y);
                    win[r][c][0] = f01.x; win[r][c][1] = f01.y;
                    win[r][c][2] = f23.x; win[r][c][3] = f23.y;
                }
            #pragma unroll
            for (int oj = 0; oj < 4; ++oj) {
                const float* wb = w2 + ((size_t)(co0 + oj) * 64 + cib * 4) * 9;
                float wt[36];
                #pragma unroll
                for (int t = 0; t < 36; ++t) wt[t] = wb[t];
                #pragma unroll
                for (int r = 0; r < 3; ++r)
                    #pragma unroll
                    for (int c = 0; c < 3; ++c)
                        #pragma unroll
                        for (int ky = 0; ky < 3; ++ky)
                            #pragma unroll
                            for (int kx = 0; kx < 3; ++kx)
                                #pragma unroll
                                for (int j = 0; j < 4; ++j)
                                    acc[r][c][oj] = fmaf(win[r + ky][c + kx][j],
                                                         wt[j * 9 + ky * 3 + kx],
                                                         acc[r][c][oj]);
            }
        }

        #pragma unroll
        for (int oj = 0; oj < 4; ++oj) {
            const int co = co0 + oj;
            const float sc = g2[co] * rsqrtf(v2[co] + EPS);
            const float sh = be2[co] - (m2[co] - b2[co]) * sc;
            #pragma unroll
            for (int r = 0; r < 3; ++r)
                #pragma unroll
                for (int c = 0; c < 3; ++c) {
                    const float v = fmaxf(fmaf(acc[r][c][oj], sc, sh), 0.f);
                    h2p[((y0 + r) * 24 + (x0 + c)) * 64 + co] = __float2half(v);
                }
        }
    }
}

// ---------------- K2: conv3 (stage h2 -> swizzled LDS, write h3 over same slot) ----------------
__global__ __launch_bounds__(512, 2)
void k_conv3k(const float* __restrict__ w3, const float* __restrict__ b3,
              const float* __restrict__ g3, const float* __restrict__ be3,
              const float* __restrict__ m3, const float* __restrict__ v3,
              __half* __restrict__ hws)
{
    extern __shared__ char smem[];  // 576 rows * 128 B = 73728 B
    const int p = blockIdx.x;
    const int tid = threadIdx.x;
    const int lane = tid & 63;
    const int wave = tid >> 6;
    __half* slot = hws + (size_t)p * SLOT;

    // stage h2 (73728 B) global-linear -> LDS-swizzled (8B-granule writes)
    for (int q = tid; q < 4608; q += 512) {
        const uint4 v = *reinterpret_cast<const uint4*>(reinterpret_cast<const char*>(slot) + (size_t)q * 16);
        const int g0 = q * 2, g1v = q * 2 + 1;
        const int pix0 = g0 >> 4, bk0 = g0 & 15;
        const int pix1 = g1v >> 4, bk1 = g1v & 15;
        *reinterpret_cast<uint2*>(smem + pix0 * 128 + ((bk0 * 8) ^ ((pix0 & 15) << 3))) = make_uint2(v.x, v.y);
        *reinterpret_cast<uint2*>(smem + pix1 * 128 + ((bk1 * 8) ^ ((pix1 & 15) << 3))) = make_uint2(v.z, v.w);
    }
    __syncthreads();   // all of h2 is in LDS; slot can now be overwritten by h3

    const int ly = lane >> 3, lx = lane & 7;
    const int y0 = ly * 3, x0 = lx * 3;   // tiles cover 24x24; only y,x < 22 valid

    for (int kco = 0; kco < 4; ++kco) {
        const int co0 = (wave + 8 * kco) * 4;
        float acc[3][3][4];
        #pragma unroll
        for (int r = 0; r < 3; ++r)
            #pragma unroll
            for (int c = 0; c < 3; ++c)
                #pragma unroll
                for (int j = 0; j < 4; ++j) acc[r][c][j] = 0.f;

        for (int cib = 0; cib < 16; ++cib) {
            const int ci8 = cib * 8;
            float win[5][5][4];
            #pragma unroll
            for (int r = 0; r < 5; ++r)
                #pragma unroll
                for (int c = 0; c < 5; ++c) {
                    int iy = y0 + r; if (iy > 23) iy = 23;   // clamped reads only feed invalid outputs
                    int ix = x0 + c; if (ix > 23) ix = 23;
                    const int pix = iy * 24 + ix;
                    const uint2 raw = *reinterpret_cast<const uint2*>(smem + lds_addr(pix, ci8));
                    const float2 f01 = h2f2(raw.x), f23 = h2f2(raw.y);
                    win[r][c][0] = f01.x; win[r][c][1] = f01.y;
                    win[r][c][2] = f23.x; win[r][c][3] = f23.y;
                }
            #pragma unroll
            for (int oj = 0; oj < 4; ++oj) {
                const float* wb = w3 + ((size_t)(co0 + oj) * 64 + cib * 4) * 9;
                float wt[36];
                #pragma unroll
                for (int t = 0; t < 36; ++t) wt[t] = wb[t];
                #pragma unroll
                for (int r = 0; r < 3; ++r)
                    #pragma unroll
                    for (int c = 0; c < 3; ++c)
                        #pragma unroll
                        for (int ky = 0; ky < 3; ++ky)
                            #pragma unroll
                            for (int kx = 0; kx < 3; ++kx)
                                #pragma unroll
                                for (int j = 0; j < 4; ++j)
                                    acc[r][c][oj] = fmaf(win[r + ky][c + kx][j],
                                                         wt[j * 9 + ky * 3 + kx],
                                                         acc[r][c][oj]);
            }
        }

        #pragma unroll
        for (int oj = 0; oj < 4; ++oj) {
            const int co = co0 + oj;
            const float sc = g3[co] * rsqrtf(v3[co] + EPS);
            const float sh = be3[co] - (m3[co] - b3[co]) * sc;
            #pragma unroll
            for (int r = 0; r < 3; ++r)
                #pragma unroll
                for (int c = 0; c < 3; ++c) {
                    const int yy = y0 + r, xx = x0 + c;
                    if (yy < 22 && xx < 22) {
                        const float v = fmaxf(fmaf(acc[r][c][oj], sc, sh), 0.f);
                        slot[co * 484 + yy * 22 + xx] = __float2half(v);  // k-order matches wf
                    }
                }
        }
    }
}

// ---------------- K0: init output with bias ----------------
__global__ void k_init(const float* __restrict__ bf, float* __restrict__ out)
{
    const int i = blockIdx.x * 256 + threadIdx.x;
    if (i < 115200) out[i] = bf[i % 100];
}

// ---------------- K3: FC, M-tile=64 x K-split=32, atomic accumulate ----------------
__global__ __launch_bounds__(256)
void k_fc(const __half* __restrict__ hws, const float* __restrict__ wf,
          float* __restrict__ out)
{
    const int bid = blockIdx.x;        // 18 * 32 = 576 blocks
    const int bm = bid % 18;
    const int ks = bid / 18;
    const int tid = threadIdx.x;
    const int m = tid & 63;            // 64 distinct patches per wave
    const int og = tid >> 6;           // wave-uniform -> wf loads broadcast
    const int o0 = og * 25;
    const int prow = bm * 64 + m;
    const int k0 = ks * 1936;          // 1936 = 121*16

    const __half* A = hws + (size_t)prow * SLOT + k0;
    const float* wfb = wf + (size_t)o0 * 61952 + k0;

    float acc[25];
    #pragma unroll
    for (int j = 0; j < 25; ++j) acc[j] = 0.f;

    for (int ch = 0; ch < 121; ++ch) {
        const uint4 r0 = *reinterpret_cast<const uint4*>(A + ch * 16);
        const uint4 r1 = *reinterpret_cast<const uint4*>(A + ch * 16 + 8);
        float a[16];
        float2 f;
        f = h2f2(r0.x); a[0] = f.x;  a[1] = f.y;
        f = h2f2(r0.y); a[2] = f.x;  a[3] = f.y;
        f = h2f2(r0.z); a[4] = f.x;  a[5] = f.y;
        f = h2f2(r0.w); a[6] = f.x;  a[7] = f.y;
        f = h2f2(r1.x); a[8] = f.x;  a[9] = f.y;
        f = h2f2(r1.y); a[10] = f.x; a[11] = f.y;
        f = h2f2(r1.z); a[12] = f.x; a[13] = f.y;
        f = h2f2(r1.w); a[14] = f.x; a[15] = f.y;

        #pragma unroll
        for (int j = 0; j < 25; ++j) {
            const float4* wp = reinterpret_cast<const float4*>(wfb + (size_t)j * 61952 + ch * 16);
            const float4 q0 = wp[0], q1 = wp[1], q2 = wp[2], q3 = wp[3];
            float s = acc[j];
            s = fmaf(a[0],  q0.x, s); s = fmaf(a[1],  q0.y, s);
            s = fmaf(a[2],  q0.z, s); s = fmaf(a[3],  q0.w, s);
            s = fmaf(a[4],  q1.x, s); s = fmaf(a[5],  q1.y, s);
            s = fmaf(a[6],  q1.z, s); s = fmaf(a[7],  q1.w, s);
            s = fmaf(a[8],  q2.x, s); s = fmaf(a[9],  q2.y, s);
            s = fmaf(a[10], q2.z, s); s = fmaf(a[11], q2.w, s);
            s = fmaf(a[12], q3.x, s); s = fmaf(a[13], q3.y, s);
            s = fmaf(a[14], q3.z, s); s = fmaf(a[15], q3.w, s);
            acc[j] = s;
        }
    }
    #pragma unroll
    for (int j = 0; j < 25; ++j)
        atomicAdd(out + (size_t)prow * 100 + o0 + j, acc[j]);
}

extern "C" void kernel_launch(void* const* d_in, const int* in_sizes, int n_in,
                              void* d_out, int out_size, void* d_ws, size_t ws_size,
                              hipStream_t stream)
{
    const float* x   = (const float*)d_in[0];
    const float* w1  = (const float*)d_in[1];
    const float* b1  = (const float*)d_in[2];
    const float* g1  = (const float*)d_in[3];
    const float* be1 = (const float*)d_in[4];
    const float* m1  = (const float*)d_in[5];
    const float* v1  = (const float*)d_in[6];
    const float* w2  = (const float*)d_in[7];
    const float* b2  = (const float*)d_in[8];
    const float* g2  = (const float*)d_in[9];
    const float* be2 = (const float*)d_in[10];
    const float* m2  = (const float*)d_in[11];
    const float* v2  = (const float*)d_in[12];
    const float* w3  = (const float*)d_in[13];
    const float* b3  = (const float*)d_in[14];
    const float* g3  = (const float*)d_in[15];
    const float* be3 = (const float*)d_in[16];
    const float* m3  = (const float*)d_in[17];
    const float* v3  = (const float*)d_in[18];
    const float* wf  = (const float*)d_in[19];
    const float* bf  = (const float*)d_in[20];

    __half* hws = (__half*)d_ws;       // needs 142,737,408 B
    float* out = (float*)d_out;

    // >64KB dynamic LDS (host-side immediate calls; graph-capture safe)
    hipFuncSetAttribute(reinterpret_cast<const void*>(k_conv12),
                        hipFuncAttributeMaxDynamicSharedMemorySize, 89664);
    hipFuncSetAttribute(reinterpret_cast<const void*>(k_conv3k),
                        hipFuncAttributeMaxDynamicSharedMemorySize, 73728);

    k_conv12<<<1152, 512, 89664, stream>>>(x, w1, b1, g1, be1, m1, v1,
                                           w2, b2, g2, be2, m2, v2, hws);
    k_conv3k<<<1152, 512, 73728, stream>>>(w3, b3, g3, be3, m3, v3, hws);
    k_init<<<450, 256, 0, stream>>>(bf, out);
    k_fc<<<576, 256, 0, stream>>>(hws, wf, out);
}

// Round 2
// 421.904 us; speedup vs baseline: 8.8044x; 8.8044x over previous
//
#include <hip/hip_runtime.h>
#include <hip/hip_fp16.h>

#define EPS 1e-5f

typedef _Float16 f16x8 __attribute__((ext_vector_type(8)));
typedef float f32x4 __attribute__((ext_vector_type(4)));

// ---- ws layout (in halfs) ----
// wfh: 128 rows x 61952 (rows 100..127 never written; garbage is discarded)
#define WFH_OFF 0ull
#define W2H_OFF 7929856ull          // 64 x 576
#define W3H_OFF 7966720ull          // 128 x 576
#define H3_OFF  8040448ull          // 1152 x 61952  (total 158,818,304 bytes)

// ---------------- prep: fp32 -> fp16 weight repacks ----------------
// w2h[co][tap*64+ci] = w2[co][ci][tap]; w3h likewise.
// wfh[o][pix*128+co] = wf[o][co*484+pix]  (k-order matches h3 [pix][co]).
__global__ __launch_bounds__(256)
void k_prep(const float* __restrict__ w2, const float* __restrict__ w3,
            const float* __restrict__ wf, __half* __restrict__ ws)
{
    const int i = blockIdx.x * 256 + threadIdx.x;
    if (i < 6195200) {                       // 100 * 61952
        const int o = i / 61952, k = i - o * 61952;
        const int co = k & 127, pix = k >> 7;
        ws[WFH_OFF + (size_t)o * 61952 + k] =
            __float2half(wf[(size_t)o * 61952 + co * 484 + pix]);
    } else if (i < 6195200 + 36864) {
        const int j = i - 6195200;
        const int co = j / 576, k = j - co * 576;
        const int tap = k >> 6, ci = k & 63;
        ws[W2H_OFF + j] = __float2half(w2[co * 576 + ci * 9 + tap]);
    } else if (i < 6195200 + 36864 + 73728) {
        const int j = i - (6195200 + 36864);
        const int co = j / 576, k = j - co * 576;
        const int tap = k >> 6, ci = k & 63;
        ws[W3H_OFF + j] = __float2half(w3[co * 576 + ci * 9 + tap]);
    }
}

// Swizzled LDS byte address: [row][ci] fp16, 128B rows, 16B-granule XOR on (row&7).
__device__ __forceinline__ int lds_addr(int row, int colByte) {
    return row * 128 + (colByte ^ ((row & 7) << 4));
}

// ---------------- fused conv1 -> conv2 -> conv3 per patch ----------------
__global__ __launch_bounds__(512, 2)
void k_conv123(const float* __restrict__ x,
               const float* __restrict__ w1, const float* __restrict__ b1,
               const float* __restrict__ g1, const float* __restrict__ be1,
               const float* __restrict__ m1, const float* __restrict__ v1,
               const float* __restrict__ b2, const float* __restrict__ g2,
               const float* __restrict__ be2, const float* __restrict__ m2,
               const float* __restrict__ v2,
               const float* __restrict__ b3, const float* __restrict__ g3,
               const float* __restrict__ be3, const float* __restrict__ m3,
               const float* __restrict__ v3,
               __half* __restrict__ ws)
{
    extern __shared__ char smem[];
    float* patch = reinterpret_cast<float*>(smem);   // 784 f32
    char* s1 = smem + 3136;                          // 676 rows x 128 B

    const int p = blockIdx.x, tid = threadIdx.x;
    const int lane = tid & 63, wave = tid >> 6;
    const int l15 = lane & 15, g = lane >> 4;

    // ---- patchify
    {
        const int b = p / 9, r9 = p - b * 9, hb = r9 / 3, wb = r9 - hb * 3;
        const float* xb = x + (size_t)b * 7056 + hb * 28 * 84 + wb * 28;
        for (int i = tid; i < 784; i += 512) {
            const int yy = i / 28, xx = i - yy * 28;
            patch[i] = xb[yy * 84 + xx];
        }
    }
    __syncthreads();

    // ---- conv1 (cin=1, VALU): s1[pix 26x26][ci 64] fp16 swizzled
    {
        const int co = lane;
        float wr[9];
        #pragma unroll
        for (int t = 0; t < 9; ++t) wr[t] = w1[co * 9 + t];
        const float sc = g1[co] * rsqrtf(v1[co] + EPS);
        const float sh = be1[co] - (m1[co] - b1[co]) * sc;
        for (int pix = wave; pix < 676; pix += 8) {
            const int yy = pix / 26, xx = pix - yy * 26;
            const float* pp = patch + yy * 28 + xx;
            float a = 0.f;
            #pragma unroll
            for (int ky = 0; ky < 3; ++ky)
                #pragma unroll
                for (int kx = 0; kx < 3; ++kx)
                    a = fmaf(pp[ky * 28 + kx], wr[ky * 3 + kx], a);
            const float v = fmaxf(fmaf(a, sc, sh), 0.f);
            *reinterpret_cast<__half*>(s1 + lds_addr(pix, co * 2)) = __float2half(v);
        }
    }
    __syncthreads();

    const __half* w2h = ws + W2H_OFF;
    const __half* w3h = ws + W3H_OFF;

    // ---- conv2 (MFMA): M=576(24x24), N=64, K=576. 36 M-tiles: waves 0-3 own 5, 4-7 own 4.
    const int mt0 = (wave < 4) ? wave * 5 : 20 + (wave - 4) * 4;
    int rb2[5];
    #pragma unroll
    for (int t = 0; t < 5; ++t) {
        const int mt = mt0 + t;
        if (mt < 36) {
            const int m = mt * 16 + l15;
            const int yy = m / 24, xx = m - yy * 24;
            rb2[t] = yy * 26 + xx;
        } else rb2[t] = 0;      // wave 7 t=4: garbage tile, store skipped
    }
    f32x4 acc2[5][4];
    #pragma unroll
    for (int t = 0; t < 5; ++t)
        #pragma unroll
        for (int nt = 0; nt < 4; ++nt) acc2[t][nt] = (f32x4)0.f;

    for (int kk = 0; kk < 18; ++kk) {       // k = tap*64 + ci, tap = kk>>1
        const int tap = kk >> 1;
        const int rowadd = (tap / 3) * 26 + (tap % 3);
        const int cbyte = (kk & 1) * 64 + g * 16;
        f16x8 bfr[4];
        #pragma unroll
        for (int nt = 0; nt < 4; ++nt)
            bfr[nt] = *reinterpret_cast<const f16x8*>(w2h + (nt * 16 + l15) * 576 + kk * 32 + g * 8);
        #pragma unroll
        for (int t = 0; t < 5; ++t) {
            const int inrow = rb2[t] + rowadd;
            const f16x8 af = *reinterpret_cast<const f16x8*>(s1 + lds_addr(inrow, cbyte));
            #pragma unroll
            for (int nt = 0; nt < 4; ++nt)
                acc2[t][nt] = __builtin_amdgcn_mfma_f32_16x16x32_f16(af, bfr[nt], acc2[t][nt], 0, 0, 0);
        }
    }
    __syncthreads();   // all waves done reading s1(conv1)

    // ---- conv2 epilogue: BN+ReLU -> h2 fp16 into same LDS region [pix 24x24][ci 64]
    {
        float sc[4], sh[4];
        #pragma unroll
        for (int nt = 0; nt < 4; ++nt) {
            const int co = nt * 16 + l15;
            const float s = g2[co] * rsqrtf(v2[co] + EPS);
            sc[nt] = s; sh[nt] = be2[co] - (m2[co] - b2[co]) * s;
        }
        #pragma unroll
        for (int t = 0; t < 5; ++t) {
            if (wave >= 4 && t == 4) continue;   // duplicate/garbage tile
            #pragma unroll
            for (int r = 0; r < 4; ++r) {
                const int pixm = (mt0 + t) * 16 + g * 4 + r;
                #pragma unroll
                for (int nt = 0; nt < 4; ++nt) {
                    const int co = nt * 16 + l15;
                    const float v = fmaxf(fmaf(acc2[t][nt][r], sc[nt], sh[nt]), 0.f);
                    *reinterpret_cast<__half*>(s1 + lds_addr(pixm, co * 2)) = __float2half(v);
                }
            }
        }
    }
    __syncthreads();

    // ---- conv3 (MFMA): M=484(22x22)->32 tiles, N=128. Wave grid 4M x 2N.
    const int wm = wave >> 1, wn = wave & 1;
    int rb3[8];
    #pragma unroll
    for (int t = 0; t < 8; ++t) {
        const int m = (wm * 8 + t) * 16 + l15;
        if (m < 484) {
            const int yy = m / 22, xx = m - yy * 22;
            rb3[t] = yy * 24 + xx;
        } else rb3[t] = 0;
    }
    f32x4 acc3[8][4];
    #pragma unroll
    for (int t = 0; t < 8; ++t)
        #pragma unroll
        for (int nt = 0; nt < 4; ++nt) acc3[t][nt] = (f32x4)0.f;

    for (int kk = 0; kk < 18; ++kk) {
        const int tap = kk >> 1;
        const int rowadd = (tap / 3) * 24 + (tap % 3);
        const int cbyte = (kk & 1) * 64 + g * 16;
        f16x8 bfr[4];
        #pragma unroll
        for (int nt = 0; nt < 4; ++nt)
            bfr[nt] = *reinterpret_cast<const f16x8*>(w3h + (wn * 64 + nt * 16 + l15) * 576 + kk * 32 + g * 8);
        #pragma unroll
        for (int t = 0; t < 8; ++t) {
            const int inrow = rb3[t] + rowadd;
            const f16x8 af = *reinterpret_cast<const f16x8*>(s1 + lds_addr(inrow, cbyte));
            #pragma unroll
            for (int nt = 0; nt < 4; ++nt)
                acc3[t][nt] = __builtin_amdgcn_mfma_f32_16x16x32_f16(af, bfr[nt], acc3[t][nt], 0, 0, 0);
        }
    }

    // ---- conv3 epilogue: BN+ReLU -> h3 fp16 to global ws [pix 484][co 128]
    {
        __half* slot = ws + H3_OFF + (size_t)p * 61952;
        float sc[4], sh[4];
        #pragma unroll
        for (int nt = 0; nt < 4; ++nt) {
            const int co = wn * 64 + nt * 16 + l15;
            const float s = g3[co] * rsqrtf(v3[co] + EPS);
            sc[nt] = s; sh[nt] = be3[co] - (m3[co] - b3[co]) * s;
        }
        #pragma unroll
        for (int t = 0; t < 8; ++t)
            #pragma unroll
            for (int r = 0; r < 4; ++r) {
                const int m = (wm * 8 + t) * 16 + g * 4 + r;
                if (m < 484) {
                    #pragma unroll
                    for (int nt = 0; nt < 4; ++nt) {
                        const int co = wn * 64 + nt * 16 + l15;
                        const float v = fmaxf(fmaf(acc3[t][nt][r], sc[nt], sh[nt]), 0.f);
                        slot[m * 128 + co] = __float2half(v);
                    }
                }
            }
    }
}

// ---------------- out = bias ----------------
__global__ void k_init(const float* __restrict__ bf, float* __restrict__ out)
{
    const int i = blockIdx.x * 256 + threadIdx.x;
    if (i < 115200) out[i] = bf[i % 100];
}

// ---------------- FC (MFMA): M=1152, N=100(pad 128), K=61952, 44 K-chunks ----------------
__global__ __launch_bounds__(256)
void k_fc(const __half* __restrict__ ws, float* __restrict__ out)
{
    const __half* h3 = ws + H3_OFF;
    const __half* wfh = ws + WFH_OFF;
    const int bid = blockIdx.x;            // 18 M-blocks x 44 K-chunks = 792
    const int mb = bid % 18, kc = bid / 18;
    const int tid = threadIdx.x, lane = tid & 63, wave = tid >> 6;
    const int wm = wave >> 1, wn = wave & 1;
    const int l15 = lane & 15, g = lane >> 4;

    const size_t kbase = (size_t)kc * 1408 + g * 8;   // 1408 = 44 k-steps * 32
    const __half* Ap[2];
    #pragma unroll
    for (int mt = 0; mt < 2; ++mt) {
        const int patchm = mb * 64 + wm * 32 + mt * 16 + l15;
        Ap[mt] = h3 + (size_t)patchm * 61952 + kbase;
    }
    const __half* Bp[4];
    #pragma unroll
    for (int nt = 0; nt < 4; ++nt) {
        const int orow = wn * 64 + nt * 16 + l15;
        Bp[nt] = wfh + (size_t)orow * 61952 + kbase;
    }

    f32x4 acc[2][4];
    #pragma unroll
    for (int mt = 0; mt < 2; ++mt)
        #pragma unroll
        for (int nt = 0; nt < 4; ++nt) acc[mt][nt] = (f32x4)0.f;

    for (int kk = 0; kk < 44; ++kk) {
        const f16x8 a0 = *reinterpret_cast<const f16x8*>(Ap[0] + kk * 32);
        const f16x8 a1 = *reinterpret_cast<const f16x8*>(Ap[1] + kk * 32);
        f16x8 b[4];
        #pragma unroll
        for (int nt = 0; nt < 4; ++nt)
            b[nt] = *reinterpret_cast<const f16x8*>(Bp[nt] + kk * 32);
        #pragma unroll
        for (int nt = 0; nt < 4; ++nt) {
            acc[0][nt] = __builtin_amdgcn_mfma_f32_16x16x32_f16(a0, b[nt], acc[0][nt], 0, 0, 0);
            acc[1][nt] = __builtin_amdgcn_mfma_f32_16x16x32_f16(a1, b[nt], acc[1][nt], 0, 0, 0);
        }
    }

    #pragma unroll
    for (int mt = 0; mt < 2; ++mt)
        #pragma unroll
        for (int nt = 0; nt < 4; ++nt) {
            const int col = wn * 64 + nt * 16 + l15;
            if (col < 100) {
                #pragma unroll
                for (int r = 0; r < 4; ++r) {
                    const int row = mb * 64 + wm * 32 + mt * 16 + g * 4 + r;
                    atomicAdd(out + (size_t)row * 100 + col, acc[mt][nt][r]);
                }
            }
        }
}

extern "C" void kernel_launch(void* const* d_in, const int* in_sizes, int n_in,
                              void* d_out, int out_size, void* d_ws, size_t ws_size,
                              hipStream_t stream)
{
    const float* x   = (const float*)d_in[0];
    const float* w1  = (const float*)d_in[1];
    const float* b1  = (const float*)d_in[2];
    const float* g1  = (const float*)d_in[3];
    const float* be1 = (const float*)d_in[4];
    const float* m1  = (const float*)d_in[5];
    const float* v1  = (const float*)d_in[6];
    const float* w2  = (const float*)d_in[7];
    const float* b2  = (const float*)d_in[8];
    const float* g2  = (const float*)d_in[9];
    const float* be2 = (const float*)d_in[10];
    const float* m2  = (const float*)d_in[11];
    const float* v2  = (const float*)d_in[12];
    const float* w3  = (const float*)d_in[13];
    const float* b3  = (const float*)d_in[14];
    const float* g3  = (const float*)d_in[15];
    const float* be3 = (const float*)d_in[16];
    const float* m3  = (const float*)d_in[17];
    const float* v3  = (const float*)d_in[18];
    const float* wf  = (const float*)d_in[19];
    const float* bf  = (const float*)d_in[20];

    __half* hws = (__half*)d_ws;     // needs 158,818,304 B
    float* out = (float*)d_out;

    hipFuncSetAttribute(reinterpret_cast<const void*>(k_conv123),
                        hipFuncAttributeMaxDynamicSharedMemorySize, 89664);

    k_prep<<<24632, 256, 0, stream>>>(w2, w3, wf, hws);
    k_conv123<<<1152, 512, 89664, stream>>>(x, w1, b1, g1, be1, m1, v1,
                                            b2, g2, be2, m2, v2,
                                            b3, g3, be3, m3, v3, hws);
    k_init<<<450, 256, 0, stream>>>(bf, out);
    k_fc<<<792, 256, 0, stream>>>(hws, out);
}